// Round 3
// baseline (593.970 us; speedup 1.0000x reference)
//
#include <hip/hip_runtime.h>
#include <hip/hip_bf16.h>

#define B_ROWS   524288
#define MEL_BINS 128
#define DIM      64
#define KCODES   128

// ---------------- workspace layout (floats) ----------------
// WT [128*64] : W_in transposed, WT[j*64+d] = W_in[d*128+j]
// n0 [128]    : np.sum(cb0*cb0, -1) emulated (f32 pairwise)
// n1 [128]    : np.sum(cb1*cb1, -1) emulated
// T0 [128*128]: cb0 @ W_out^T (fp64-accum, f32 store)
// T1 [128*128]
#define WS_WT 0
#define WS_N0 (WS_WT + MEL_BINS*DIM)        // 8192
#define WS_N1 (WS_N0 + KCODES)              // 8320
#define WS_T0 (WS_N1 + KCODES)              // 8448
#define WS_T1 (WS_T0 + KCODES*MEL_BINS)     // 24832
#define WS_TOT (WS_T1 + KCODES*MEL_BINS)    // 41216 floats = 164864 B

// numpy pairwise_sum (scalar path) for n=64 contiguous, applied to v[d]*v[d].
// Elementwise square is rounded separately (np materializes the temp), then
// 8 stride-8 accumulators, fixed combine tree. contract(off) keeps mul+add
// from fusing into fma.
__device__ __forceinline__ float np_pairwise64_sq(const float* v) {
#pragma clang fp contract(off)
    float r0 = v[0]*v[0], r1 = v[1]*v[1], r2 = v[2]*v[2], r3 = v[3]*v[3];
    float r4 = v[4]*v[4], r5 = v[5]*v[5], r6 = v[6]*v[6], r7 = v[7]*v[7];
#pragma unroll
    for (int i = 8; i < 64; i += 8) {
        r0 += v[i+0]*v[i+0]; r1 += v[i+1]*v[i+1];
        r2 += v[i+2]*v[i+2]; r3 += v[i+3]*v[i+3];
        r4 += v[i+4]*v[i+4]; r5 += v[i+5]*v[i+5];
        r6 += v[i+6]*v[i+6]; r7 += v[i+7]*v[i+7];
    }
    return ((r0 + r1) + (r2 + r3)) + ((r4 + r5) + (r6 + r7));
}

__global__ __launch_bounds__(256) void rvq_precomp(
    const float* __restrict__ W_in, const float* __restrict__ cb0,
    const float* __restrict__ cb1, const float* __restrict__ W_out,
    float* __restrict__ ws)
{
#pragma clang fp contract(off)
    float* WT = ws + WS_WT;
    float* n0 = ws + WS_N0;
    float* n1 = ws + WS_N1;
    float* T0 = ws + WS_T0;
    float* T1 = ws + WS_T1;

    int tid = blockIdx.x * 256 + threadIdx.x;
    if (tid < 16384) {                       // T0[i][m] (loose 2% threshold -> fp64 accum fine)
        int i = tid >> 7, m = tid & 127;
        double a = 0.0;
        for (int d = 0; d < DIM; ++d)
            a = fma((double)cb0[i*DIM + d], (double)W_out[m*DIM + d], a);
        T0[tid] = (float)a;
    } else if (tid < 32768) {                // T1[i][m]
        int t = tid - 16384;
        int i = t >> 7, m = t & 127;
        double a = 0.0;
        for (int d = 0; d < DIM; ++d)
            a = fma((double)cb1[i*DIM + d], (double)W_out[m*DIM + d], a);
        T1[t] = (float)a;
    } else if (tid < 40960) {                // WT[j][d] = W_in[d][j]
        int t = tid - 32768;
        int j = t >> 6, d = t & 63;
        WT[t] = W_in[d*MEL_BINS + j];
    } else if (tid < 41216) {                // n0 / n1 via exact np pairwise emulation
        int t = tid - 40960;                 // 0..255
        const float* cb = (t & 128) ? cb1 : cb0;
        float*       nn = (t & 128) ? n1  : n0;
        int k = t & 127;
        nn[k] = np_pairwise64_sq(cb + k*DIM);
    }
}

__global__ __launch_bounds__(256) void rvq_main(
    const float* __restrict__ mel,
    const float* __restrict__ b_in,
    const float* __restrict__ cb0,
    const float* __restrict__ cb1,
    const float* __restrict__ b_out,
    const float* __restrict__ ws,
    float* __restrict__ out_mel,
    float* __restrict__ out_idx)
{
#pragma clang fp contract(off)
    const float* __restrict__ WT = ws + WS_WT;
    const float* __restrict__ n0 = ws + WS_N0;
    const float* __restrict__ n1 = ws + WS_N1;
    const float* __restrict__ T0 = ws + WS_T0;
    const float* __restrict__ T1 = ws + WS_T1;

    const int b = blockIdx.x * 256 + threadIdx.x;

    // ---- z = mel @ W_in^T : sgemm emulation, ascending-k fused-fma from 0
    float z[DIM];
#pragma unroll
    for (int d = 0; d < DIM; ++d) z[d] = 0.f;

    const float4* melr = reinterpret_cast<const float4*>(mel + (size_t)b * MEL_BINS);
    for (int jc = 0; jc < MEL_BINS / 4; ++jc) {
        float4 m4 = melr[jc];
        const float* w = WT + jc * 4 * DIM;    // wave-uniform -> scalar loads
#pragma unroll
        for (int d = 0; d < DIM; ++d) z[d] = fmaf(w[d],         m4.x, z[d]);
#pragma unroll
        for (int d = 0; d < DIM; ++d) z[d] = fmaf(w[DIM + d],   m4.y, z[d]);
#pragma unroll
        for (int d = 0; d < DIM; ++d) z[d] = fmaf(w[2*DIM + d], m4.z, z[d]);
#pragma unroll
        for (int d = 0; d < DIM; ++d) z[d] = fmaf(w[3*DIM + d], m4.w, z[d]);
    }
    // ---- + b_in : separate rounded add (np adds bias after the matmul)
#pragma unroll
    for (int d = 0; d < DIM; ++d) z[d] = z[d] + b_in[d];

    // ================= codebook 0 =================
    // sum_rr = np.sum(r*r) : exact pairwise emulation on register array
    float s0 = z[0]*z[0], s1 = z[1]*z[1], s2 = z[2]*z[2], s3 = z[3]*z[3];
    float s4 = z[4]*z[4], s5 = z[5]*z[5], s6 = z[6]*z[6], s7 = z[7]*z[7];
#pragma unroll
    for (int i = 8; i < 64; i += 8) {
        s0 += z[i+0]*z[i+0]; s1 += z[i+1]*z[i+1];
        s2 += z[i+2]*z[i+2]; s3 += z[i+3]*z[i+3];
        s4 += z[i+4]*z[i+4]; s5 += z[i+5]*z[i+5];
        s6 += z[i+6]*z[i+6]; s7 += z[i+7]*z[i+7];
    }
    float sum_rr = ((s0 + s1) + (s2 + s3)) + ((s4 + s5) + (s6 + s7));

    float best0 = 3.4e38f; int i0 = 0;
#pragma unroll 2
    for (int k = 0; k < KCODES; ++k) {
        const float* c = cb0 + k * DIM;        // wave-uniform -> scalar loads
        float acc = 0.f;
#pragma unroll
        for (int d = 0; d < DIM; ++d) acc = fmaf(c[d], z[d], acc);  // ascending d, 1 accumulator
        float dist = (sum_rr - 2.0f*acc) + n0[k];   // np: (A - B) + C, each rounded
        if (dist < best0) { best0 = dist; i0 = k; } // strict < = first-min (np.argmin)
    }

    // residual = r - code : elementwise rounded sub (per-lane gather, L1-hot 32 KB)
    {
        const float* c = cb0 + (size_t)i0 * DIM;
#pragma unroll
        for (int d = 0; d < DIM; ++d) z[d] = z[d] - c[d];
    }

    // ================= codebook 1 =================
    s0 = z[0]*z[0]; s1 = z[1]*z[1]; s2 = z[2]*z[2]; s3 = z[3]*z[3];
    s4 = z[4]*z[4]; s5 = z[5]*z[5]; s6 = z[6]*z[6]; s7 = z[7]*z[7];
#pragma unroll
    for (int i = 8; i < 64; i += 8) {
        s0 += z[i+0]*z[i+0]; s1 += z[i+1]*z[i+1];
        s2 += z[i+2]*z[i+2]; s3 += z[i+3]*z[i+3];
        s4 += z[i+4]*z[i+4]; s5 += z[i+5]*z[i+5];
        s6 += z[i+6]*z[i+6]; s7 += z[i+7]*z[i+7];
    }
    sum_rr = ((s0 + s1) + (s2 + s3)) + ((s4 + s5) + (s6 + s7));

    float best1 = 3.4e38f; int i1 = 0;
#pragma unroll 2
    for (int k = 0; k < KCODES; ++k) {
        const float* c = cb1 + k * DIM;
        float acc = 0.f;
#pragma unroll
        for (int d = 0; d < DIM; ++d) acc = fmaf(c[d], z[d], acc);
        float dist = (sum_rr - 2.0f*acc) + n1[k];
        if (dist < best1) { best1 = dist; i1 = k; }
    }

    // ---- decode: out = T0[i0] + T1[i1] + b_out (2% threshold: table path is fine)
    const float4* t0r = reinterpret_cast<const float4*>(T0 + (size_t)i0 * MEL_BINS);
    const float4* t1r = reinterpret_cast<const float4*>(T1 + (size_t)i1 * MEL_BINS);
    float4* outr = reinterpret_cast<float4*>(out_mel + (size_t)b * MEL_BINS);
#pragma unroll 4
    for (int q = 0; q < MEL_BINS / 4; ++q) {
        float4 a = t0r[q], c = t1r[q];
        float4 o;
        o.x = a.x + c.x + b_out[4*q + 0];
        o.y = a.y + c.y + b_out[4*q + 1];
        o.z = a.z + c.z + b_out[4*q + 2];
        o.w = a.w + c.w + b_out[4*q + 3];
        outr[q] = o;
    }

    out_idx[2*(size_t)b + 0] = (float)i0;
    out_idx[2*(size_t)b + 1] = (float)i1;
}

extern "C" void kernel_launch(void* const* d_in, const int* in_sizes, int n_in,
                              void* d_out, int out_size, void* d_ws, size_t ws_size,
                              hipStream_t stream)
{
    const float* mel   = (const float*)d_in[0];   // (B, 128)
    const float* W_in  = (const float*)d_in[1];   // (64, 128)
    const float* b_in  = (const float*)d_in[2];   // (64,)
    const float* cb0   = (const float*)d_in[3];   // (128, 64)
    const float* cb1   = (const float*)d_in[4];   // (128, 64)
    const float* W_out = (const float*)d_in[5];   // (128, 64)
    const float* b_out = (const float*)d_in[6];   // (128,)

    float* ws      = (float*)d_ws;                 // 164864 bytes used
    float* out_mel = (float*)d_out;                // B*128 floats
    float* out_idx = (float*)d_out + (size_t)B_ROWS * MEL_BINS;  // B*2

    rvq_precomp<<<(WS_TOT + 255) / 256, 256, 0, stream>>>(W_in, cb0, cb1, W_out, ws);
    rvq_main<<<B_ROWS / 256, 256, 0, stream>>>(mel, b_in, cb0, cb1, b_out, ws,
                                               out_mel, out_idx);
}